// Round 8
// baseline (305.570 us; speedup 1.0000x reference)
//
#include <hip/hip_runtime.h>
#include <cstdint>

// BFP quantize: block = channel vector at each (n,h,w), NCHW layout.
// N=64, C=256, H=W=56, mantissa_bits=3.
// delta = 2^(e-3), max_abs = m*2^e, m in [0.5,1) (frexp). q = trunc(x/delta)*delta.
// Exact pow2 arithmetic — absmax==0 verified R1/R2/R3b/R5/R6/R7.
//
// R8 = R6 ∪ R7 lessons:
//  - full-line granules (R6): lane l -> site j=l&7 (8 x 16B = one aligned 128B
//    line per channel; image base & site-block both 128B-aligned since HW4%8==0),
//    channel-group g=l>>3. FETCH/WRITE measured 1.0x with this shape.
//  - float4 loads (R6 vs R7): 1KB/instruction per outstanding-load slot; R7's
//    scalar loads starved MLP (12KB in flight -> 3.5 TB/s).
//  - two-sweep + L3 re-read (R1/R7: FETCH exactly 1.000x): no v[32] array,
//    low VGPR -> 8 waves/SIMD.
//  - NO LDS / barriers (vs R6): lane sweeps 32 channels c = g + 8i, butterfly
//    masks 8/16/32 closes all 256 channels in-wave. 6272 independent waves.

constexpr int C      = 256;
constexpr int HW     = 56 * 56;    // 3136
constexpr int HW4    = HW / 4;     // 784 float4 per (n,c) plane (98 x 8)
constexpr int CHW4   = C * HW4;    // float4 per image
constexpr int STRIDE = 8 * HW4;    // +8 channels, in float4 units

__device__ __forceinline__ int fexp(float x) {
    int e;
    (void)frexpf(x, &e);           // v_frexp_exp_i32_f32; e=0 for x==0
    return e;
}

__device__ __forceinline__ void fmax4(float4& m, const float4& v) {
    m.x = fmaxf(m.x, fabsf(v.x));
    m.y = fmaxf(m.y, fabsf(v.y));
    m.z = fmaxf(m.z, fabsf(v.z));
    m.w = fmaxf(m.w, fabsf(v.w));
}

__global__ __launch_bounds__(256, 8)
void bfp_kernel(const float4* __restrict__ in, float4* __restrict__ out) {
    const int l  = threadIdx.x & 63;
    const int w  = threadIdx.x >> 6;
    const int j  = l & 7;                 // site within this wave's 8-site line
    const int g  = l >> 3;                // channel sub-group 0..7
    const int sg = blockIdx.x * 4 + w;    // site-group (8 float4 sites)

    const int s  = sg * 8 + j;            // float4 site; group never straddles
    const int n  = s / HW4;               //   images (HW4 % 8 == 0)
    const int s4 = s - n * HW4;

    const float4* p = in  + (size_t)n * CHW4 + (size_t)g * HW4 + s4;
    float4*       q = out + (size_t)n * CHW4 + (size_t)g * HW4 + s4;

    // ---- pass A: abs-max over this lane's 32 channels (c = g + 8i) ----
    float4 a0 = make_float4(0.f, 0.f, 0.f, 0.f), a1 = a0, a2 = a0, a3 = a0;
#pragma unroll
    for (int i = 0; i < 32; i += 8) {
        float4 x0 = p[(i + 0) * STRIDE], x1 = p[(i + 1) * STRIDE];
        float4 x2 = p[(i + 2) * STRIDE], x3 = p[(i + 3) * STRIDE];
        float4 x4 = p[(i + 4) * STRIDE], x5 = p[(i + 5) * STRIDE];
        float4 x6 = p[(i + 6) * STRIDE], x7 = p[(i + 7) * STRIDE];
        fmax4(a0, x0); fmax4(a1, x1); fmax4(a2, x2); fmax4(a3, x3);
        fmax4(a0, x4); fmax4(a1, x5); fmax4(a2, x6); fmax4(a3, x7);
    }
    float4 m;
    m.x = fmaxf(fmaxf(a0.x, a1.x), fmaxf(a2.x, a3.x));
    m.y = fmaxf(fmaxf(a0.y, a1.y), fmaxf(a2.y, a3.y));
    m.z = fmaxf(fmaxf(a0.z, a1.z), fmaxf(a2.z, a3.z));
    m.w = fmaxf(fmaxf(a0.w, a1.w), fmaxf(a2.w, a3.w));

    // ---- butterfly across the 8 channel-groups sharing site j (no LDS) ----
#pragma unroll
    for (int mask = 8; mask < 64; mask <<= 1) {
        m.x = fmaxf(m.x, __shfl_xor(m.x, mask));
        m.y = fmaxf(m.y, __shfl_xor(m.y, mask));
        m.z = fmaxf(m.z, __shfl_xor(m.z, mask));
        m.w = fmaxf(m.w, __shfl_xor(m.w, mask));
    }

    // ---- shared exponent -> delta = 2^(e-3), inv = 2^(3-e) (both exact) ----
    const int ex = fexp(m.x), ey = fexp(m.y), ez = fexp(m.z), ew = fexp(m.w);
    const float dx = ldexpf(1.f, ex - 3), ix = ldexpf(1.f, 3 - ex);
    const float dy = ldexpf(1.f, ey - 3), iy = ldexpf(1.f, 3 - ey);
    const float dz = ldexpf(1.f, ez - 3), iz = ldexpf(1.f, 3 - ez);
    const float dw = ldexpf(1.f, ew - 3), iw = ldexpf(1.f, 3 - ew);

    // ---- pass B: re-read (L3-hit, proven R1/R7), quantize, store ----
#pragma unroll
    for (int i = 0; i < 32; i += 8) {
        float4 v[8];
#pragma unroll
        for (int k = 0; k < 8; ++k) v[k] = p[(i + k) * STRIDE];
#pragma unroll
        for (int k = 0; k < 8; ++k) {
            float4 r;
            r.x = truncf(v[k].x * ix) * dx;
            r.y = truncf(v[k].y * iy) * dy;
            r.z = truncf(v[k].z * iz) * dz;
            r.w = truncf(v[k].w * iw) * dw;
            q[(i + k) * STRIDE] = r;
        }
    }
}

extern "C" void kernel_launch(void* const* d_in, const int* in_sizes, int n_in,
                              void* d_out, int out_size, void* d_ws, size_t ws_size,
                              hipStream_t stream) {
    const float* in = (const float*)d_in[0];
    float* out      = (float*)d_out;
    int total4 = in_sizes[0] / (4 * C);    // 50176 float4 sites
    int blocks = total4 / 32;              // 1568 blocks (4 waves x 8 sites), exact
    bfp_kernel<<<blocks, 256, 0, stream>>>((const float4*)in, (float4*)out);
}